// Round 8
// baseline (322.799 us; speedup 1.0000x reference)
//
#include <hip/hip_runtime.h>

// Problem collapse: T=1, H=1, h0=c0=0 => Wh/f-gate dead; conv => pointwise
// matmul with Wx[(kh-1)//2,0,:,:]. 4 layers fused, split-bf16 MFMA
// (hi*hi+hi*lo+lo*hi ~ 2^-18 rel err). Wave-autonomous: each wave owns 16
// positions, computes all 192 channels, chains layers through wave-private
// LDS -> ZERO __syncthreads in the whole kernel (same-wave DS ops are
// program-ordered). Then D1 GEMM (split-bf16 MFMA) + reduce + D2.

#define POS 131072
#define SH 72   // LDS row stride in shorts (144 B): A-frag b128 reads land at
                // exactly-minimum bank aliasing (8 lanes/bank-group)

typedef __attribute__((ext_vector_type(8))) short bf16x8;
typedef __attribute__((ext_vector_type(4))) float f32x4;

__device__ __forceinline__ unsigned short f2bf_rn(float f) {
    unsigned u = __float_as_uint(f);
    u += 0x7FFF + ((u >> 16) & 1);
    return (unsigned short)(u >> 16);
}
__device__ __forceinline__ float bf2f(unsigned short h) {
    return __uint_as_float(((unsigned)h) << 16);
}
__device__ __forceinline__ float hsig(float x) {
    return fminf(fmaxf(fmaf(x, 0.2f, 0.5f), 0.0f), 1.0f);
}
__device__ __forceinline__ float tanh_e(float x) {
    float t = __expf(2.0f * x);
    return 1.0f - __fdividef(2.0f, t + 1.0f);
}

// Layer weights -> transposed split-bf16: per layer [hi:192x64][lo:192x64],
// row = g*64 + ch (== nt*16 + tx for n-tile nt). Grid 12 = 4 layers x 3 gates.
__global__ __launch_bounds__(256) void prep_w(
    const float* __restrict__ W1, const float* __restrict__ W2,
    const float* __restrict__ W3, const float* __restrict__ W4,
    unsigned short* __restrict__ WT)
{
    const int bid = blockIdx.x;
    const int ll = bid / 3;
    const int g  = bid - ll * 3;
    const float* W = (ll == 0) ? (W1 + 4 * 16384) :
                     (ll == 1) ? (W2 + 2 * 16384) :
                     (ll == 2) ? (W3 + 4 * 16384) : (W4 + 2 * 16384);
    const int gofs = (g == 0) ? 0 : ((g == 1) ? 128 : 192);
    unsigned short* hi = WT + ll * (2 * 192 * 64) + (g * 64) * 64;
    unsigned short* lo = hi + 192 * 64;
    const int n  = threadIdx.x & 63;
    const int c0 = threadIdx.x >> 6;
    #pragma unroll
    for (int cc = 0; cc < 16; cc++) {
        int c = cc * 4 + c0;
        float w = W[c * 256 + gofs + n];
        unsigned short h = f2bf_rn(w);
        hi[n * 64 + c] = h;
        lo[n * 64 + c] = f2bf_rn(w - bf2f(h));
    }
}

// Fused 4-layer stack; wave = 16 positions x all 192 channels; no barriers.
__global__ __launch_bounds__(256) void fused_mfma(
    const float* __restrict__ x,
    const unsigned short* __restrict__ WT,
    const float* __restrict__ B1, const float* __restrict__ B2,
    const float* __restrict__ B3, const float* __restrict__ B4,
    unsigned short* __restrict__ h4hi, unsigned short* __restrict__ h4lo)
{
    __shared__ unsigned short Hhi[4][16][SH];   // wave-private [pos][ch]
    __shared__ unsigned short Hlo[4][16][SH];

    const int t = threadIdx.x;
    const int lane = t & 63;
    const int w = t >> 6;
    const int tx = lane & 15;
    const int quad = lane >> 4;
    const int pw = blockIdx.x * 64 + w * 16;   // wave's first position

    // Stage this wave's 16 positions of x -> split-bf16 planes.
    {
        const float4* xv = (const float4*)(x + (size_t)pw * 64);
        #pragma unroll
        for (int it = 0; it < 4; it++) {
            int lin4 = it * 64 + lane;          // float4 id in 16x64 tile
            int p = lin4 >> 4;
            int c0 = (lin4 & 15) * 4;
            float4 v = xv[lin4];
            const float* vp = (const float*)&v;
            unsigned short h0 = f2bf_rn(vp[0]), h1 = f2bf_rn(vp[1]);
            unsigned short h2 = f2bf_rn(vp[2]), h3 = f2bf_rn(vp[3]);
            unsigned hh01 = (unsigned)h0 | ((unsigned)h1 << 16);
            unsigned hh23 = (unsigned)h2 | ((unsigned)h3 << 16);
            unsigned ll01 = (unsigned)f2bf_rn(vp[0] - bf2f(h0)) |
                            ((unsigned)f2bf_rn(vp[1] - bf2f(h1)) << 16);
            unsigned ll23 = (unsigned)f2bf_rn(vp[2] - bf2f(h2)) |
                            ((unsigned)f2bf_rn(vp[3] - bf2f(h3)) << 16);
            *(uint2*)&Hhi[w][p][c0] = make_uint2(hh01, hh23);
            *(uint2*)&Hlo[w][p][c0] = make_uint2(ll01, ll23);
        }
    }
    // No barrier: wave-private LDS, same-wave DS ops are ordered.

    #pragma unroll 1
    for (int l = 0; l < 4; l++) {
        const unsigned short* wl = WT + l * (2 * 192 * 64);
        const float* Bb = (l == 0) ? B1 : (l == 1) ? B2 : (l == 2) ? B3 : B4;

        // acc[nt]: n-tiles 0-3 = i (ch 0..63), 4-7 = g, 8-11 = o.
        f32x4 acc[12];
        #pragma unroll
        for (int nt = 0; nt < 12; nt++) {
            int chg = ((nt & 3) * 16) + tx;
            int off = (nt < 4) ? chg : ((nt < 8) ? 128 + chg : 192 + chg);
            float bv = Bb[off];
            acc[nt] = (f32x4){bv, bv, bv, bv};
        }

        #pragma unroll
        for (int ks = 0; ks < 2; ks++) {
            bf16x8 Ah = *(const bf16x8*)&Hhi[w][tx][ks * 32 + quad * 8];
            bf16x8 Al = *(const bf16x8*)&Hlo[w][tx][ks * 32 + quad * 8];
            #pragma unroll
            for (int nt = 0; nt < 12; nt++) {
                const unsigned short* bp =
                    wl + (nt * 16 + tx) * 64 + ks * 32 + quad * 8;
                bf16x8 Bh = *(const bf16x8*)bp;
                bf16x8 Bl = *(const bf16x8*)(bp + 192 * 64);
                acc[nt] = __builtin_amdgcn_mfma_f32_16x16x32_bf16(Ah, Bh, acc[nt], 0, 0, 0);
                acc[nt] = __builtin_amdgcn_mfma_f32_16x16x32_bf16(Ah, Bl, acc[nt], 0, 0, 0);
                acc[nt] = __builtin_amdgcn_mfma_f32_16x16x32_bf16(Al, Bh, acc[nt], 0, 0, 0);
            }
        }

        // Gate combine (all three gates lane-local) + write next-layer input.
        #pragma unroll
        for (int nt = 0; nt < 4; nt++)
            #pragma unroll
            for (int r = 0; r < 4; r++) {
                float cs = hsig(acc[nt][r]) * tanh_e(acc[nt + 4][r]);
                float h  = hsig(acc[nt + 8][r]) * tanh_e(cs);
                int p  = quad * 4 + r;
                int ch = nt * 16 + tx;
                unsigned short hh = f2bf_rn(h);
                Hhi[w][p][ch] = hh;
                Hlo[w][p][ch] = f2bf_rn(h - bf2f(hh));
            }
        // No barrier: next iteration's ds_reads are same-wave ordered.
    }

    // Coalesced writeout of this wave's 16x64 split-bf16 tile.
    #pragma unroll
    for (int it = 0; it < 2; it++) {
        int lin8 = it * 64 + lane;             // 8-short chunk id (128 total)
        int p = lin8 >> 3;
        int c0 = (lin8 & 7) * 8;
        size_t g = (size_t)(pw + p) * 64 + c0;
        *(uint4*)(h4hi + g) = *(const uint4*)&Hhi[w][p][c0];
        *(uint4*)(h4lo + g) = *(const uint4*)&Hlo[w][p][c0];
    }
}

// D1 partial GEMM, split-bf16 MFMA. Block = K-chunk of 128 (2 subs of 64).
// A (64 batches x K) staged in LDS; B = D1w gathered straight from global
// (each 256B row read exactly once per block) and split in registers.
__global__ __launch_bounds__(256) void d1_mfma(
    const unsigned short* __restrict__ Ahig, const unsigned short* __restrict__ Alog,
    const float* __restrict__ Bw, float* __restrict__ part)
{
    __shared__ unsigned short Ahi[64][SH], Alo[64][SH];
    const int t = threadIdx.x;
    const int kb = blockIdx.x;
    const int lane = t & 63, w = t >> 6;
    const int tx = lane & 15, quad = lane >> 4;
    const int n = 16 * w + tx;

    f32x4 acc[4];
    #pragma unroll
    for (int m = 0; m < 4; m++) acc[m] = (f32x4){0.0f, 0.0f, 0.0f, 0.0f};

    #pragma unroll
    for (int sub = 0; sub < 2; sub++) {
        const int k0 = kb * 128 + sub * 64;
        if (sub) __syncthreads();
        #pragma unroll
        for (int i = 0; i < 2; i++) {
            int lin8 = t + i * 256;
            int row = lin8 >> 3;
            int c0 = (lin8 & 7) * 8;
            size_t g = (size_t)row * 131072 + k0 + c0;
            *(uint4*)&Ahi[row][c0] = *(const uint4*)(Ahig + g);
            *(uint4*)&Alo[row][c0] = *(const uint4*)(Alog + g);
        }
        __syncthreads();

        #pragma unroll
        for (int ks = 0; ks < 2; ks++) {
            bf16x8 Bh, Bl;
            #pragma unroll
            for (int j = 0; j < 8; j++) {
                float bv = Bw[(size_t)(k0 + ks * 32 + quad * 8 + j) * 64 + n];
                unsigned short hb = f2bf_rn(bv);
                Bh[j] = (short)hb;
                Bl[j] = (short)f2bf_rn(bv - bf2f(hb));
            }
            #pragma unroll
            for (int m = 0; m < 4; m++) {
                bf16x8 Ah = *(const bf16x8*)&Ahi[m * 16 + tx][ks * 32 + quad * 8];
                bf16x8 Al = *(const bf16x8*)&Alo[m * 16 + tx][ks * 32 + quad * 8];
                acc[m] = __builtin_amdgcn_mfma_f32_16x16x32_bf16(Ah, Bh, acc[m], 0, 0, 0);
                acc[m] = __builtin_amdgcn_mfma_f32_16x16x32_bf16(Ah, Bl, acc[m], 0, 0, 0);
                acc[m] = __builtin_amdgcn_mfma_f32_16x16x32_bf16(Al, Bh, acc[m], 0, 0, 0);
            }
        }
    }

    float* dst = part + (size_t)kb * 4096;
    #pragma unroll
    for (int m = 0; m < 4; m++)
        #pragma unroll
        for (int r = 0; r < 4; r++)
            dst[(m * 16 + quad * 4 + r) * 64 + n] = acc[m][r];
}

// Reduce 1024 tiles + D1b, relu, dot D2w, + D2b. 64 blocks x 1024.
__global__ __launch_bounds__(1024) void d1_reduce(
    const float* __restrict__ part, const float* __restrict__ D1b,
    const float* __restrict__ D2w, const float* __restrict__ D2b,
    float* __restrict__ out)
{
    __shared__ float red[16][64];
    const int b = blockIdx.x;
    const int t = threadIdx.x;
    const int j = t & 63, s = t >> 6;
    float acc = 0.0f;
    #pragma unroll 4
    for (int m = 0; m < 64; m++)
        acc += part[(size_t)(s + 16 * m) * 4096 + b * 64 + j];
    red[s][j] = acc;
    __syncthreads();
    if (t < 64) {
        float v = D1b[t];
        #pragma unroll
        for (int s2 = 0; s2 < 16; s2++) v += red[s2][t];
        v = fmaxf(v, 0.0f) * D2w[t];
        #pragma unroll
        for (int off = 32; off > 0; off >>= 1)
            v += __shfl_down(v, off, 64);
        if (t == 0) out[b] = v + D2b[0];
    }
}

extern "C" void kernel_launch(void* const* d_in, const int* in_sizes, int n_in,
                              void* d_out, int out_size, void* d_ws, size_t ws_size,
                              hipStream_t stream) {
    (void)in_sizes; (void)n_in; (void)out_size; (void)ws_size;
    const float* x   = (const float*)d_in[0];
    const float* W1x = (const float*)d_in[1];
    const float* b1  = (const float*)d_in[3];
    const float* W2x = (const float*)d_in[4];
    const float* b2  = (const float*)d_in[6];
    const float* W3x = (const float*)d_in[7];
    const float* b3  = (const float*)d_in[9];
    const float* W4x = (const float*)d_in[10];
    const float* b4  = (const float*)d_in[12];
    const float* D1w = (const float*)d_in[13];
    const float* D1b = (const float*)d_in[14];
    const float* D2w = (const float*)d_in[15];
    const float* D2b = (const float*)d_in[16];
    float* out = (float*)d_out;

    unsigned short* h4hi = (unsigned short*)d_ws;            // 16.8 MB
    unsigned short* h4lo = h4hi + (size_t)POS * 64;          // 16.8 MB
    float* part = (float*)(h4lo + (size_t)POS * 64);         // 16.8 MB
    unsigned short* WT = (unsigned short*)(part + (size_t)1024 * 4096);  // 384 KB

    prep_w<<<dim3(12), dim3(256), 0, stream>>>(W1x, W2x, W3x, W4x, WT);
    fused_mfma<<<dim3(POS / 64), dim3(256), 0, stream>>>(
        x, WT, b1, b2, b3, b4, h4hi, h4lo);
    d1_mfma<<<dim3(1024), dim3(256), 0, stream>>>(h4hi, h4lo, D1w, part);
    d1_reduce<<<dim3(64), dim3(1024), 0, stream>>>(part, D1b, D2w, D2b, out);
}

// Round 9
// 213.536 us; speedup vs baseline: 1.5117x; 1.5117x over previous
//
#include <hip/hip_runtime.h>

// Problem collapse: T=1, H=1, h0=c0=0 => Wh/f-gate dead; conv => pointwise
// matmul with Wx[(kh-1)//2,0,:,:]. 4 layers fused (split-bf16 MFMA,
// hi*hi+hi*lo+lo*hi ~ 2^-18 rel err; r5 structure = measured optimum).
// D1 GEMM: D1w pre-split/transposed to [n][k] bf16 planes so B-frags are
// single b128 global reads; A staged in LDS. Then reduce + D2.

#define POS 131072
#define SH 80    // fused/LDS row stride (shorts) — r5 measured config
#define SA 136   // d1 A-stage row stride for 128-k windows (16B multiple)

typedef __attribute__((ext_vector_type(8))) short bf16x8;
typedef __attribute__((ext_vector_type(4))) float f32x4;

__device__ __forceinline__ unsigned short f2bf_rn(float f) {
    unsigned u = __float_as_uint(f);
    u += 0x7FFF + ((u >> 16) & 1);
    return (unsigned short)(u >> 16);
}
__device__ __forceinline__ float bf2f(unsigned short h) {
    return __uint_as_float(((unsigned)h) << 16);
}
__device__ __forceinline__ float hsig(float x) {
    return fminf(fmaxf(fmaf(x, 0.2f, 0.5f), 0.0f), 1.0f);
}
__device__ __forceinline__ float tanh_e(float x) {
    float t = __expf(2.0f * x);
    return 1.0f - __fdividef(2.0f, t + 1.0f);
}

// Layer weights -> transposed split-bf16: per layer [hi:192x64][lo:192x64],
// row = g*64 + n. Grid 12 = 4 layers x 3 gates.
__global__ __launch_bounds__(256) void prep_w(
    const float* __restrict__ W1, const float* __restrict__ W2,
    const float* __restrict__ W3, const float* __restrict__ W4,
    unsigned short* __restrict__ WT)
{
    const int bid = blockIdx.x;
    const int ll = bid / 3;
    const int g  = bid - ll * 3;
    const float* W = (ll == 0) ? (W1 + 4 * 16384) :
                     (ll == 1) ? (W2 + 2 * 16384) :
                     (ll == 2) ? (W3 + 4 * 16384) : (W4 + 2 * 16384);
    const int gofs = (g == 0) ? 0 : ((g == 1) ? 128 : 192);
    unsigned short* hi = WT + ll * (2 * 192 * 64) + (g * 64) * 64;
    unsigned short* lo = hi + 192 * 64;
    const int n  = threadIdx.x & 63;
    const int c0 = threadIdx.x >> 6;
    #pragma unroll
    for (int cc = 0; cc < 16; cc++) {
        int c = cc * 4 + c0;
        float w = W[c * 256 + gofs + n];
        unsigned short h = f2bf_rn(w);
        hi[n * 64 + c] = h;
        lo[n * 64 + c] = f2bf_rn(w - bf2f(h));
    }
}

// D1w (131072,64) fp32 -> split-bf16 planes in [n][k] layout (transposed).
// Block = 128-k window; grid 1024.
__global__ __launch_bounds__(256) void prep_d1(
    const float* __restrict__ D1w,
    unsigned short* __restrict__ Bhig, unsigned short* __restrict__ Blog)
{
    __shared__ unsigned short Thi[64][SA], Tlo[64][SA];
    const int t = threadIdx.x;
    const int k0 = blockIdx.x * 128;
    #pragma unroll
    for (int i = 0; i < 8; i++) {
        int lin4 = t + i * 256;            // float4 id in 128 x 16
        int kk = lin4 >> 4;
        int j0 = (lin4 & 15) * 4;
        float4 v = *(const float4*)(D1w + (size_t)(k0 + kk) * 64 + j0);
        const float* vp = (const float*)&v;
        #pragma unroll
        for (int q = 0; q < 4; q++) {
            unsigned short h = f2bf_rn(vp[q]);
            Thi[j0 + q][kk] = h;
            Tlo[j0 + q][kk] = f2bf_rn(vp[q] - bf2f(h));
        }
    }
    __syncthreads();
    #pragma unroll
    for (int i = 0; i < 4; i++) {
        int lin = t + i * 256;             // uint4 id in 64 x 16
        int nr = lin >> 4;
        int c8 = (lin & 15) * 8;
        size_t g = (size_t)nr * 131072 + k0 + c8;
        *(uint4*)(Bhig + g) = *(const uint4*)&Thi[nr][c8];
        *(uint4*)(Blog + g) = *(const uint4*)&Tlo[nr][c8];
    }
}

// Fused 4-layer gated pointwise stack (round-5 verbatim: measured 86.5 us).
// Block = 64 positions, 4 waves; wave w owns output channels 16w..16w+15.
__global__ __launch_bounds__(256) void fused_mfma(
    const float* __restrict__ x,
    const unsigned short* __restrict__ WT,
    const float* __restrict__ B1, const float* __restrict__ B2,
    const float* __restrict__ B3, const float* __restrict__ B4,
    unsigned short* __restrict__ h4hi, unsigned short* __restrict__ h4lo)
{
    __shared__ unsigned short Hhi[64][SH];
    __shared__ unsigned short Hlo[64][SH];

    const int t = threadIdx.x;
    const int lane = t & 63;
    const int w = t >> 6;
    const int tx = lane & 15;
    const int quad = lane >> 4;
    const int n = 16 * w + tx;
    const int pbase = blockIdx.x * 64;

    // Stage x -> split-bf16 LDS (transposed per-position rows).
    {
        const float4* xv = (const float4*)(x + (size_t)pbase * 64);
        #pragma unroll
        for (int k = 0; k < 4; k++) {
            int lin4 = t + k * 256;
            int p = lin4 >> 4;
            int c0 = (lin4 & 15) * 4;
            float4 v = xv[lin4];
            const float* vp = (const float*)&v;
            unsigned short h0 = f2bf_rn(vp[0]), h1 = f2bf_rn(vp[1]);
            unsigned short h2 = f2bf_rn(vp[2]), h3 = f2bf_rn(vp[3]);
            unsigned hh01 = (unsigned)h0 | ((unsigned)h1 << 16);
            unsigned hh23 = (unsigned)h2 | ((unsigned)h3 << 16);
            unsigned ll01 = (unsigned)f2bf_rn(vp[0] - bf2f(h0)) |
                            ((unsigned)f2bf_rn(vp[1] - bf2f(h1)) << 16);
            unsigned ll23 = (unsigned)f2bf_rn(vp[2] - bf2f(h2)) |
                            ((unsigned)f2bf_rn(vp[3] - bf2f(h3)) << 16);
            *(uint2*)&Hhi[p][c0] = make_uint2(hh01, hh23);
            *(uint2*)&Hlo[p][c0] = make_uint2(ll01, ll23);
        }
    }
    __syncthreads();

    #pragma unroll 1
    for (int l = 0; l < 4; l++) {
        const unsigned short* wl = WT + l * (2 * 192 * 64);
        const float* Bb = (l == 0) ? B1 : (l == 1) ? B2 : (l == 2) ? B3 : B4;
        const float bi = Bb[n];
        const float bg = Bb[128 + n];
        const float bo = Bb[192 + n];

        f32x4 acc[4][3];
        #pragma unroll
        for (int m = 0; m < 4; m++) {
            acc[m][0] = (f32x4){bi, bi, bi, bi};
            acc[m][1] = (f32x4){bg, bg, bg, bg};
            acc[m][2] = (f32x4){bo, bo, bo, bo};
        }

        #pragma unroll
        for (int ks = 0; ks < 2; ks++) {
            bf16x8 Bh[3], Bl[3];
            #pragma unroll
            for (int g = 0; g < 3; g++) {
                const unsigned short* bp = wl + (g * 64 + n) * 64 + ks * 32 + quad * 8;
                Bh[g] = *(const bf16x8*)bp;
                Bl[g] = *(const bf16x8*)(bp + 192 * 64);
            }
            #pragma unroll
            for (int m = 0; m < 4; m++) {
                bf16x8 Ah = *(const bf16x8*)&Hhi[m * 16 + tx][ks * 32 + quad * 8];
                bf16x8 Al = *(const bf16x8*)&Hlo[m * 16 + tx][ks * 32 + quad * 8];
                #pragma unroll
                for (int g = 0; g < 3; g++) {
                    acc[m][g] = __builtin_amdgcn_mfma_f32_16x16x32_bf16(Ah, Bh[g], acc[m][g], 0, 0, 0);
                    acc[m][g] = __builtin_amdgcn_mfma_f32_16x16x32_bf16(Ah, Bl[g], acc[m][g], 0, 0, 0);
                    acc[m][g] = __builtin_amdgcn_mfma_f32_16x16x32_bf16(Al, Bh[g], acc[m][g], 0, 0, 0);
                }
            }
        }

        // Epilogue compute in registers.
        float hv[4][4];
        #pragma unroll
        for (int m = 0; m < 4; m++)
            #pragma unroll
            for (int r = 0; r < 4; r++) {
                float cs = hsig(acc[m][0][r]) * tanh_e(acc[m][1][r]);
                hv[m][r] = hsig(acc[m][2][r]) * tanh_e(cs);
            }

        __syncthreads();   // all A-reads of Hhi/Hlo done -> safe to overwrite
        #pragma unroll
        for (int m = 0; m < 4; m++)
            #pragma unroll
            for (int r = 0; r < 4; r++) {
                int p = m * 16 + quad * 4 + r;
                unsigned short hh = f2bf_rn(hv[m][r]);
                Hhi[p][n] = hh;
                Hlo[p][n] = f2bf_rn(hv[m][r] - bf2f(hh));
            }
        __syncthreads();
    }

    // Coalesced copy-out of split-bf16 h4 planes.
    #pragma unroll
    for (int i = 0; i < 2; i++) {
        int lin8 = t + i * 256;
        int p = lin8 >> 3;
        int c0 = (lin8 & 7) * 8;
        uint4 vh = *(const uint4*)&Hhi[p][c0];
        uint4 vl = *(const uint4*)&Hlo[p][c0];
        size_t g = (size_t)(pbase + p) * 64 + c0;
        *(uint4*)(h4hi + g) = vh;
        *(uint4*)(h4lo + g) = vl;
    }
}

// D1 partial GEMM, split-bf16 MFMA. Block = K-chunk of 256 (2 subs of 128).
// A staged in LDS (coalesced); B-frags are direct b128 global reads from the
// pre-split [n][k] planes (each 128B line read exactly once, by one wave).
__global__ __launch_bounds__(256) void d1_mfma(
    const unsigned short* __restrict__ Ahig, const unsigned short* __restrict__ Alog,
    const unsigned short* __restrict__ Bhig, const unsigned short* __restrict__ Blog,
    float* __restrict__ part)
{
    __shared__ unsigned short Ahi[64][SA], Alo[64][SA];
    const int t = threadIdx.x;
    const int kb = blockIdx.x;
    const int lane = t & 63, w = t >> 6;
    const int tx = lane & 15, quad = lane >> 4;
    const int n = 16 * w + tx;

    f32x4 acc[4];
    #pragma unroll
    for (int m = 0; m < 4; m++) acc[m] = (f32x4){0.0f, 0.0f, 0.0f, 0.0f};

    #pragma unroll
    for (int sub = 0; sub < 2; sub++) {
        const int k0 = kb * 256 + sub * 128;
        if (sub) __syncthreads();
        // Stage A planes: 64 rows x 128 shorts = 1024 uint4 each.
        #pragma unroll
        for (int i = 0; i < 4; i++) {
            int lin = t + i * 256;
            int row = lin >> 4;
            int c8 = (lin & 15) * 8;
            size_t g = (size_t)row * 131072 + k0 + c8;
            *(uint4*)&Ahi[row][c8] = *(const uint4*)(Ahig + g);
            *(uint4*)&Alo[row][c8] = *(const uint4*)(Alog + g);
        }
        __syncthreads();

        #pragma unroll
        for (int ks = 0; ks < 4; ks++) {
            size_t boff = (size_t)n * 131072 + k0 + ks * 32 + quad * 8;
            bf16x8 Bh = *(const bf16x8*)(Bhig + boff);
            bf16x8 Bl = *(const bf16x8*)(Blog + boff);
            #pragma unroll
            for (int m = 0; m < 4; m++) {
                bf16x8 Ah = *(const bf16x8*)&Ahi[m * 16 + tx][ks * 32 + quad * 8];
                bf16x8 Al = *(const bf16x8*)&Alo[m * 16 + tx][ks * 32 + quad * 8];
                acc[m] = __builtin_amdgcn_mfma_f32_16x16x32_bf16(Ah, Bh, acc[m], 0, 0, 0);
                acc[m] = __builtin_amdgcn_mfma_f32_16x16x32_bf16(Ah, Bl, acc[m], 0, 0, 0);
                acc[m] = __builtin_amdgcn_mfma_f32_16x16x32_bf16(Al, Bh, acc[m], 0, 0, 0);
            }
        }
    }

    float* dst = part + (size_t)kb * 4096;
    #pragma unroll
    for (int m = 0; m < 4; m++)
        #pragma unroll
        for (int r = 0; r < 4; r++)
            dst[(m * 16 + quad * 4 + r) * 64 + n] = acc[m][r];
}

// Reduce 512 tiles + D1b, relu, dot D2w, + D2b. 64 blocks x 1024.
__global__ __launch_bounds__(1024) void d1_reduce(
    const float* __restrict__ part, const float* __restrict__ D1b,
    const float* __restrict__ D2w, const float* __restrict__ D2b,
    float* __restrict__ out)
{
    __shared__ float red[16][64];
    const int b = blockIdx.x;
    const int t = threadIdx.x;
    const int j = t & 63, s = t >> 6;
    float acc = 0.0f;
    #pragma unroll 4
    for (int m = 0; m < 32; m++)
        acc += part[(size_t)(s + 16 * m) * 4096 + b * 64 + j];
    red[s][j] = acc;
    __syncthreads();
    if (t < 64) {
        float v = D1b[t];
        #pragma unroll
        for (int s2 = 0; s2 < 16; s2++) v += red[s2][t];
        v = fmaxf(v, 0.0f) * D2w[t];
        #pragma unroll
        for (int off = 32; off > 0; off >>= 1)
            v += __shfl_down(v, off, 64);
        if (t == 0) out[b] = v + D2b[0];
    }
}

extern "C" void kernel_launch(void* const* d_in, const int* in_sizes, int n_in,
                              void* d_out, int out_size, void* d_ws, size_t ws_size,
                              hipStream_t stream) {
    (void)in_sizes; (void)n_in; (void)out_size; (void)ws_size;
    const float* x   = (const float*)d_in[0];
    const float* W1x = (const float*)d_in[1];
    const float* b1  = (const float*)d_in[3];
    const float* W2x = (const float*)d_in[4];
    const float* b2  = (const float*)d_in[6];
    const float* W3x = (const float*)d_in[7];
    const float* b3  = (const float*)d_in[9];
    const float* W4x = (const float*)d_in[10];
    const float* b4  = (const float*)d_in[12];
    const float* D1w = (const float*)d_in[13];
    const float* D1b = (const float*)d_in[14];
    const float* D2w = (const float*)d_in[15];
    const float* D2b = (const float*)d_in[16];
    float* out = (float*)d_out;

    unsigned short* h4hi = (unsigned short*)d_ws;                 // 16.8 MB
    unsigned short* h4lo = h4hi + (size_t)POS * 64;               // 16.8 MB
    float* part = (float*)(h4lo + (size_t)POS * 64);              // 8.4 MB
    unsigned short* WT   = (unsigned short*)(part + (size_t)512 * 4096);  // 384 KB
    unsigned short* Bhig = WT + 4 * 2 * 192 * 64;                 // 16.8 MB
    unsigned short* Blog = Bhig + (size_t)64 * 131072;            // 16.8 MB

    prep_w<<<dim3(12), dim3(256), 0, stream>>>(W1x, W2x, W3x, W4x, WT);
    prep_d1<<<dim3(1024), dim3(256), 0, stream>>>(D1w, Bhig, Blog);
    fused_mfma<<<dim3(POS / 64), dim3(256), 0, stream>>>(
        x, WT, b1, b2, b3, b4, h4hi, h4lo);
    d1_mfma<<<dim3(512), dim3(256), 0, stream>>>(h4hi, h4lo, Bhig, Blog, part);
    d1_reduce<<<dim3(64), dim3(1024), 0, stream>>>(part, D1b, D2w, D2b, out);
}

// Round 10
// 211.147 us; speedup vs baseline: 1.5288x; 1.0113x over previous
//
#include <hip/hip_runtime.h>

// Problem collapse: T=1, H=1, h0=c0=0 => Wh/f-gate dead; conv => pointwise
// matmul with Wx[(kh-1)//2,0,:,:]. MEGA kernel: block = one t-slice across
// all 64 batches -> 4 fused gated layers (split-bf16 MFMA, r5 structure)
// + the block's 64x64x64 D1 partial GEMM (D1w slice staged/split in LDS),
// so h4 never touches HBM. Then one reduce kernel (sum 2048 tiles + D1b +
// relu + dot D2w + D2b).

#define POS 131072
#define SH 80   // H-plane row stride (shorts) — r5 measured config
#define SB 72   // B-slice row stride (shorts), 144 B = 16B-aligned

typedef __attribute__((ext_vector_type(8))) short bf16x8;
typedef __attribute__((ext_vector_type(4))) float f32x4;

__device__ __forceinline__ unsigned short f2bf_rn(float f) {
    unsigned u = __float_as_uint(f);
    u += 0x7FFF + ((u >> 16) & 1);
    return (unsigned short)(u >> 16);
}
__device__ __forceinline__ float bf2f(unsigned short h) {
    return __uint_as_float(((unsigned)h) << 16);
}
__device__ __forceinline__ float hsig(float x) {
    return fminf(fmaxf(fmaf(x, 0.2f, 0.5f), 0.0f), 1.0f);
}
__device__ __forceinline__ float tanh_e(float x) {
    float t = __expf(2.0f * x);
    return 1.0f - __fdividef(2.0f, t + 1.0f);
}

// Layer weights -> transposed split-bf16: per layer [hi:192x64][lo:192x64],
// row = g*64 + n. Grid 12 = 4 layers x 3 gates.
__global__ __launch_bounds__(256) void prep_w(
    const float* __restrict__ W1, const float* __restrict__ W2,
    const float* __restrict__ W3, const float* __restrict__ W4,
    unsigned short* __restrict__ WT)
{
    const int bid = blockIdx.x;
    const int ll = bid / 3;
    const int g  = bid - ll * 3;
    const float* W = (ll == 0) ? (W1 + 4 * 16384) :
                     (ll == 1) ? (W2 + 2 * 16384) :
                     (ll == 2) ? (W3 + 4 * 16384) : (W4 + 2 * 16384);
    const int gofs = (g == 0) ? 0 : ((g == 1) ? 128 : 192);
    unsigned short* hi = WT + ll * (2 * 192 * 64) + (g * 64) * 64;
    unsigned short* lo = hi + 192 * 64;
    const int n  = threadIdx.x & 63;
    const int c0 = threadIdx.x >> 6;
    #pragma unroll
    for (int cc = 0; cc < 16; cc++) {
        int c = cc * 4 + c0;
        float w = W[c * 256 + gofs + n];
        unsigned short h = f2bf_rn(w);
        hi[n * 64 + c] = h;
        lo[n * 64 + c] = f2bf_rn(w - bf2f(h));
    }
}

// MEGA: 4 gated layers + D1 partial. Grid 2048 = t-slices; block covers
// positions p = b*2048 + bid for b in [0,64). 4 waves; wave w owns output
// channels 16w..16w+15 in the layer loop and j-columns 16w..16w+15 in D1.
__global__ __launch_bounds__(256) void mega(
    const float* __restrict__ x,
    const unsigned short* __restrict__ WT,
    const float* __restrict__ B1, const float* __restrict__ B2,
    const float* __restrict__ B3, const float* __restrict__ B4,
    const float* __restrict__ D1w, float* __restrict__ part)
{
    __shared__ unsigned short Hhi[64][SH];
    __shared__ unsigned short Hlo[64][SH];
    __shared__ unsigned short Bhi[64][SB];   // D1w slice, [j][c] split-bf16
    __shared__ unsigned short Blo[64][SB];

    const int t = threadIdx.x;
    const int lane = t & 63;
    const int w = t >> 6;
    const int tx = lane & 15;
    const int quad = lane >> 4;
    const int n = 16 * w + tx;
    const int bid = blockIdx.x;          // t-slice index, 0..2047

    // Stage x -> split-bf16 LDS. Row b of the tile = position b*2048+bid.
    {
        const float4* xv = (const float4*)x;
        #pragma unroll
        for (int k = 0; k < 4; k++) {
            int lin4 = t + k * 256;            // float4 id in 64x16
            int b = lin4 >> 4;
            int c4 = lin4 & 15;
            float4 v = xv[((size_t)b * 2048 + bid) * 16 + c4];
            int c0 = c4 * 4;
            const float* vp = (const float*)&v;
            unsigned short h0 = f2bf_rn(vp[0]), h1 = f2bf_rn(vp[1]);
            unsigned short h2 = f2bf_rn(vp[2]), h3 = f2bf_rn(vp[3]);
            unsigned hh01 = (unsigned)h0 | ((unsigned)h1 << 16);
            unsigned hh23 = (unsigned)h2 | ((unsigned)h3 << 16);
            unsigned ll01 = (unsigned)f2bf_rn(vp[0] - bf2f(h0)) |
                            ((unsigned)f2bf_rn(vp[1] - bf2f(h1)) << 16);
            unsigned ll23 = (unsigned)f2bf_rn(vp[2] - bf2f(h2)) |
                            ((unsigned)f2bf_rn(vp[3] - bf2f(h3)) << 16);
            *(uint2*)&Hhi[b][c0] = make_uint2(hh01, hh23);
            *(uint2*)&Hlo[b][c0] = make_uint2(ll01, ll23);
        }
    }
    __syncthreads();

    #pragma unroll 1
    for (int l = 0; l < 4; l++) {
        const unsigned short* wl = WT + l * (2 * 192 * 64);
        const float* Bb = (l == 0) ? B1 : (l == 1) ? B2 : (l == 2) ? B3 : B4;
        const float bi = Bb[n];
        const float bg = Bb[128 + n];
        const float bo = Bb[192 + n];

        f32x4 acc[4][3];
        #pragma unroll
        for (int m = 0; m < 4; m++) {
            acc[m][0] = (f32x4){bi, bi, bi, bi};
            acc[m][1] = (f32x4){bg, bg, bg, bg};
            acc[m][2] = (f32x4){bo, bo, bo, bo};
        }

        #pragma unroll
        for (int ks = 0; ks < 2; ks++) {
            bf16x8 Bh[3], Bl[3];
            #pragma unroll
            for (int g = 0; g < 3; g++) {
                const unsigned short* bp = wl + (g * 64 + n) * 64 + ks * 32 + quad * 8;
                Bh[g] = *(const bf16x8*)bp;
                Bl[g] = *(const bf16x8*)(bp + 192 * 64);
            }
            #pragma unroll
            for (int m = 0; m < 4; m++) {
                bf16x8 Ah = *(const bf16x8*)&Hhi[m * 16 + tx][ks * 32 + quad * 8];
                bf16x8 Al = *(const bf16x8*)&Hlo[m * 16 + tx][ks * 32 + quad * 8];
                #pragma unroll
                for (int g = 0; g < 3; g++) {
                    acc[m][g] = __builtin_amdgcn_mfma_f32_16x16x32_bf16(Ah, Bh[g], acc[m][g], 0, 0, 0);
                    acc[m][g] = __builtin_amdgcn_mfma_f32_16x16x32_bf16(Ah, Bl[g], acc[m][g], 0, 0, 0);
                    acc[m][g] = __builtin_amdgcn_mfma_f32_16x16x32_bf16(Al, Bh[g], acc[m][g], 0, 0, 0);
                }
            }
        }

        // Epilogue compute in registers.
        float hv[4][4];
        #pragma unroll
        for (int m = 0; m < 4; m++)
            #pragma unroll
            for (int r = 0; r < 4; r++) {
                float cs = hsig(acc[m][0][r]) * tanh_e(acc[m][1][r]);
                hv[m][r] = hsig(acc[m][2][r]) * tanh_e(cs);
            }

        __syncthreads();   // all A-reads of Hhi/Hlo done -> safe to overwrite
        #pragma unroll
        for (int m = 0; m < 4; m++)
            #pragma unroll
            for (int r = 0; r < 4; r++) {
                int p = m * 16 + quad * 4 + r;
                unsigned short hh = f2bf_rn(hv[m][r]);
                Hhi[p][n] = hh;
                Hlo[p][n] = f2bf_rn(hv[m][r] - bf2f(hh));
            }
        __syncthreads();
    }

    // Stage D1w slice: rows k = bid*64 + c (c in 0..63), cols j ->
    // transposed split-bf16 Bhi/Blo[j][c].
    #pragma unroll
    for (int i = 0; i < 4; i++) {
        int lin4 = t + i * 256;                // float4 id in 64(c) x 16
        int c = lin4 >> 4;
        int j0 = (lin4 & 15) * 4;
        float4 v = *(const float4*)(D1w + ((size_t)bid * 64 + c) * 64 + j0);
        const float* vp = (const float*)&v;
        #pragma unroll
        for (int q = 0; q < 4; q++) {
            unsigned short h = f2bf_rn(vp[q]);
            Bhi[j0 + q][c] = h;
            Blo[j0 + q][c] = f2bf_rn(vp[q] - bf2f(h));
        }
    }
    __syncthreads();

    // D1 partial: C[b][j] = sum_c h[b][c] * D1w[bid*64+c][j], split-bf16.
    f32x4 accd[4];
    #pragma unroll
    for (int m = 0; m < 4; m++) accd[m] = (f32x4){0.0f, 0.0f, 0.0f, 0.0f};
    #pragma unroll
    for (int ks = 0; ks < 2; ks++) {
        bf16x8 Bh = *(const bf16x8*)&Bhi[n][ks * 32 + quad * 8];
        bf16x8 Bl = *(const bf16x8*)&Blo[n][ks * 32 + quad * 8];
        #pragma unroll
        for (int m = 0; m < 4; m++) {
            bf16x8 Ah = *(const bf16x8*)&Hhi[m * 16 + tx][ks * 32 + quad * 8];
            bf16x8 Al = *(const bf16x8*)&Hlo[m * 16 + tx][ks * 32 + quad * 8];
            accd[m] = __builtin_amdgcn_mfma_f32_16x16x32_bf16(Ah, Bh, accd[m], 0, 0, 0);
            accd[m] = __builtin_amdgcn_mfma_f32_16x16x32_bf16(Ah, Bl, accd[m], 0, 0, 0);
            accd[m] = __builtin_amdgcn_mfma_f32_16x16x32_bf16(Al, Bh, accd[m], 0, 0, 0);
        }
    }
    float* dst = part + (size_t)bid * 4096;
    #pragma unroll
    for (int m = 0; m < 4; m++)
        #pragma unroll
        for (int r = 0; r < 4; r++)
            dst[(m * 16 + quad * 4 + r) * 64 + n] = accd[m][r];
}

// Reduce 2048 tiles + D1b, relu, dot D2w, + D2b. 64 blocks x 1024.
__global__ __launch_bounds__(1024) void d1_reduce(
    const float* __restrict__ part, const float* __restrict__ D1b,
    const float* __restrict__ D2w, const float* __restrict__ D2b,
    float* __restrict__ out)
{
    __shared__ float red[16][64];
    const int b = blockIdx.x;
    const int t = threadIdx.x;
    const int j = t & 63, s = t >> 6;
    float acc = 0.0f;
    #pragma unroll 4
    for (int m = 0; m < 128; m++)
        acc += part[(size_t)(s + 16 * m) * 4096 + b * 64 + j];
    red[s][j] = acc;
    __syncthreads();
    if (t < 64) {
        float v = D1b[t];
        #pragma unroll
        for (int s2 = 0; s2 < 16; s2++) v += red[s2][t];
        v = fmaxf(v, 0.0f) * D2w[t];
        #pragma unroll
        for (int off = 32; off > 0; off >>= 1)
            v += __shfl_down(v, off, 64);
        if (t == 0) out[b] = v + D2b[0];
    }
}

extern "C" void kernel_launch(void* const* d_in, const int* in_sizes, int n_in,
                              void* d_out, int out_size, void* d_ws, size_t ws_size,
                              hipStream_t stream) {
    (void)in_sizes; (void)n_in; (void)out_size; (void)ws_size;
    const float* x   = (const float*)d_in[0];
    const float* W1x = (const float*)d_in[1];
    const float* b1  = (const float*)d_in[3];
    const float* W2x = (const float*)d_in[4];
    const float* b2  = (const float*)d_in[6];
    const float* W3x = (const float*)d_in[7];
    const float* b3  = (const float*)d_in[9];
    const float* W4x = (const float*)d_in[10];
    const float* b4  = (const float*)d_in[12];
    const float* D1w = (const float*)d_in[13];
    const float* D1b = (const float*)d_in[14];
    const float* D2w = (const float*)d_in[15];
    const float* D2b = (const float*)d_in[16];
    float* out = (float*)d_out;

    float* part = (float*)d_ws;                                 // 33.5 MB
    unsigned short* WT = (unsigned short*)(part + (size_t)2048 * 4096);  // 384 KB

    prep_w<<<dim3(12), dim3(256), 0, stream>>>(W1x, W2x, W3x, W4x, WT);
    mega<<<dim3(2048), dim3(256), 0, stream>>>(
        x, WT, b1, b2, b3, b4, D1w, part);
    d1_reduce<<<dim3(64), dim3(1024), 0, stream>>>(part, D1b, D2w, D2b, out);
}